// Round 1
// baseline (526.712 us; speedup 1.0000x reference)
//
#include <hip/hip_runtime.h>
#include <math.h>

#define BATCH 16
#define NH 32
#define KVH 8
#define NREP 4
#define HD 128
#define BS 16
#define BPS 256
#define MAXSEQ 4096
#define CHUNK 512
#define CBLK (CHUNK / BS) /* 32 */
#define ATT_SCALE 0.08838834764831845f
#define REC (NREP * HD + 2 * NREP) /* 520 floats per partial record */

// ---------------------------------------------------------------------------
// Kernel 1: scatter new K/V tokens into the flat-slot view of the caches.
// ---------------------------------------------------------------------------
__global__ __launch_bounds__(256) void kv_scatter(
    const float* __restrict__ k, const float* __restrict__ v,
    const int* __restrict__ slot_mapping,
    float* __restrict__ k_cache, float* __restrict__ v_cache) {
  int b = blockIdx.x;
  int slot = slot_mapping[b];
  size_t base = (size_t)slot * (KVH * HD);
  for (int i = threadIdx.x; i < KVH * HD; i += 256) {
    k_cache[base + i] = k[b * KVH * HD + i];
    v_cache[base + i] = v[b * KVH * HD + i];
  }
}

// ---------------------------------------------------------------------------
// Kernel 2: flash-decode with split-K over the sequence.
// grid = (nsplits, KVH, BATCH), block = 256 threads (4 waves).
// Each block: span = MAXSEQ/nsplits tokens, processed in 512-token chunks
// with online-softmax rescaling. 4 Q-heads (GQA group) share each KV read.
// ---------------------------------------------------------------------------
__global__ __launch_bounds__(256) void attn_decode(
    const float* __restrict__ q,
    const float* __restrict__ k_cache,
    const float* __restrict__ v_cache,
    const int* __restrict__ block_tables,
    const int* __restrict__ context_lens,
    float* __restrict__ part,   // [B][KVH][nsplits][REC]
    float* __restrict__ out,    // used directly when nsplits == 1
    int nsplits) {
  const int split = blockIdx.x;
  const int kvh   = blockIdx.y;
  const int b     = blockIdx.z;
  const int tid   = threadIdx.x;
  const int ctx   = context_lens[b];
  const int span  = MAXSEQ / nsplits;
  const int s_begin = split * span;

  float* rec = part + (((size_t)b * KVH + kvh) * nsplits + split) * REC;

  if (s_begin >= ctx) {
    if (nsplits > 1 && tid < NREP) {
      rec[NREP * HD + tid] = -INFINITY;        // m
      rec[NREP * HD + NREP + tid] = 0.f;       // l
    }
    return;
  }
  const int s_end = min(ctx, s_begin + span);

  __shared__ float sc[NREP][CHUNK];     // 8 KB: scores -> probabilities
  __shared__ int   btab[CBLK];          // physical block ids for this chunk
  __shared__ float red[8][NREP * HD];   // 16 KB: PV group reduction
  __shared__ float m_sh[NREP], l_sh[NREP], alpha_sh[NREP];

  const int wave = tid >> 6;
  const int lane = tid & 63;
  const int half = lane >> 5;     // which token of the wave's pair
  const int l32  = lane & 31;     // 32 lanes cover 128 dims as float4
  const int grp  = tid >> 5;      // 8 PV groups of 32 lanes
  const int gl   = tid & 31;

  // Per-lane Q fragments: 4 heads x float4 (dims l32*4 .. +3)
  float4 q4[NREP];
#pragma unroll
  for (int h = 0; h < NREP; ++h)
    q4[h] = *(const float4*)(q + ((size_t)b * NH + kvh * NREP + h) * HD + l32 * 4);

  if (tid < NREP) { m_sh[tid] = -INFINITY; l_sh[tid] = 0.f; }

  float acc[NREP][4];
#pragma unroll
  for (int h = 0; h < NREP; ++h)
#pragma unroll
    for (int j = 0; j < 4; ++j) acc[h][j] = 0.f;

  for (int c0 = s_begin; c0 < s_end; c0 += CHUNK) {
    const int n_tok = min(s_end - c0, CHUNK);

    __syncthreads();  // previous chunk's PV reads of sc/btab done; m_sh init visible
    if (tid < CBLK) {
      int bi = (c0 >> 4) + tid;
      btab[tid] = (bi < BPS) ? block_tables[b * BPS + bi] : 0;
    }
    __syncthreads();

    // ---- Phase A: scores. Each wave handles 2 tokens/iter (one per half).
    for (int t = wave * 2 + half; t < n_tok; t += 8) {
      int blk = btab[t >> 4];
      const float4 kk = *(const float4*)(
          k_cache + ((size_t)blk * BS + (t & 15)) * (KVH * HD) + kvh * HD + l32 * 4);
      float p0 = kk.x * q4[0].x + kk.y * q4[0].y + kk.z * q4[0].z + kk.w * q4[0].w;
      float p1 = kk.x * q4[1].x + kk.y * q4[1].y + kk.z * q4[1].z + kk.w * q4[1].w;
      float p2 = kk.x * q4[2].x + kk.y * q4[2].y + kk.z * q4[2].z + kk.w * q4[2].w;
      float p3 = kk.x * q4[3].x + kk.y * q4[3].y + kk.z * q4[3].z + kk.w * q4[3].w;
#pragma unroll
      for (int off = 1; off < 32; off <<= 1) {  // reduce within each 32-lane half
        p0 += __shfl_xor(p0, off);
        p1 += __shfl_xor(p1, off);
        p2 += __shfl_xor(p2, off);
        p3 += __shfl_xor(p3, off);
      }
      if (l32 == 0) {
        sc[0][t] = p0 * ATT_SCALE;
        sc[1][t] = p1 * ATT_SCALE;
        sc[2][t] = p2 * ATT_SCALE;
        sc[3][t] = p3 * ATT_SCALE;
      }
    }
    __syncthreads();

    // ---- Phase B: online softmax stats; wave w owns head w.
    {
      const int h = wave;
      float mloc = -INFINITY;
      for (int t = lane; t < n_tok; t += 64) mloc = fmaxf(mloc, sc[h][t]);
#pragma unroll
      for (int off = 1; off < 64; off <<= 1) mloc = fmaxf(mloc, __shfl_xor(mloc, off));
      float m_old = m_sh[h];
      float m_new = fmaxf(m_old, mloc);  // finite: chunk has >=1 valid token
      float sum = 0.f;
      for (int t = lane; t < n_tok; t += 64) {
        float e = __expf(sc[h][t] - m_new);
        sc[h][t] = e;
        sum += e;
      }
#pragma unroll
      for (int off = 1; off < 64; off <<= 1) sum += __shfl_xor(sum, off);
      if (lane == 0) {
        float alpha = (m_old == -INFINITY) ? 0.f : __expf(m_old - m_new);
        alpha_sh[h] = alpha;
        l_sh[h] = l_sh[h] * alpha + sum;
        m_sh[h] = m_new;
      }
    }
    __syncthreads();

    // ---- Phase C: PV accumulate. 8 groups of 32 lanes; group g owns tokens
    // t ≡ g (mod 8); 32 lanes x float4 cover the 128 dims.
    {
      float a[NREP] = {alpha_sh[0], alpha_sh[1], alpha_sh[2], alpha_sh[3]};
#pragma unroll
      for (int h = 0; h < NREP; ++h)
#pragma unroll
        for (int j = 0; j < 4; ++j) acc[h][j] *= a[h];
      for (int t = grp; t < n_tok; t += 8) {
        int blk = btab[t >> 4];
        const float4 vv = *(const float4*)(
            v_cache + ((size_t)blk * BS + (t & 15)) * (KVH * HD) + kvh * HD + gl * 4);
#pragma unroll
        for (int h = 0; h < NREP; ++h) {
          float pp = sc[h][t];
          acc[h][0] += pp * vv.x;
          acc[h][1] += pp * vv.y;
          acc[h][2] += pp * vv.z;
          acc[h][3] += pp * vv.w;
        }
      }
    }
  }

  // ---- Reduce the 8 PV groups and emit.
#pragma unroll
  for (int h = 0; h < NREP; ++h)
#pragma unroll
    for (int j = 0; j < 4; ++j) red[grp][h * HD + gl * 4 + j] = acc[h][j];
  __syncthreads();

  for (int o = tid; o < NREP * HD; o += 256) {
    float s = 0.f;
#pragma unroll
    for (int g = 0; g < 8; ++g) s += red[g][o];
    int h = o >> 7, d = o & 127;
    if (nsplits == 1) {
      out[((size_t)b * NH + kvh * NREP + h) * HD + d] = s / l_sh[h];
    } else {
      rec[o] = s;
    }
  }
  if (nsplits > 1 && tid < NREP) {
    rec[NREP * HD + tid] = m_sh[tid];
    rec[NREP * HD + NREP + tid] = l_sh[tid];
  }
}

// ---------------------------------------------------------------------------
// Kernel 3: merge split partials. grid = (KVH, BATCH), block = 256.
// ---------------------------------------------------------------------------
__global__ __launch_bounds__(256) void attn_combine(
    const float* __restrict__ part, float* __restrict__ out, int nsplits) {
  const int kvh = blockIdx.x;
  const int b   = blockIdx.y;
  const int tid = threadIdx.x;
  const float* base = part + ((size_t)b * KVH + kvh) * nsplits * REC;

  __shared__ float w_sh[8][NREP];
  __shared__ float L_sh[NREP];

  if (tid < NREP) {
    const int h = tid;
    float M = -INFINITY;
    for (int s = 0; s < nsplits; ++s)
      M = fmaxf(M, base[s * REC + NREP * HD + h]);
    float L = 0.f;
    for (int s = 0; s < nsplits; ++s) {
      float m = base[s * REC + NREP * HD + h];
      float l = base[s * REC + NREP * HD + NREP + h];
      float w = (l > 0.f) ? __expf(m - M) : 0.f;
      w_sh[s][h] = w;
      L += l * w;
    }
    L_sh[h] = L;
  }
  __syncthreads();

  for (int o = tid; o < NREP * HD; o += 256) {
    int h = o >> 7, d = o & 127;
    float s = 0.f;
    for (int sp = 0; sp < nsplits; ++sp) {
      float w = w_sh[sp][h];
      if (w > 0.f) s += w * base[sp * REC + o];
    }
    out[((size_t)b * NH + kvh * NREP + h) * HD + d] = s / L_sh[h];
  }
}

// ---------------------------------------------------------------------------
extern "C" void kernel_launch(void* const* d_in, const int* in_sizes, int n_in,
                              void* d_out, int out_size, void* d_ws, size_t ws_size,
                              hipStream_t stream) {
  const float* q = (const float*)d_in[0];
  const float* k = (const float*)d_in[1];
  const float* v = (const float*)d_in[2];
  float* k_cache = (float*)d_in[3];  // mutated; harness restores before each run
  float* v_cache = (float*)d_in[4];
  const int* block_tables = (const int*)d_in[5];
  const int* context_lens = (const int*)d_in[6];
  const int* slot_mapping = (const int*)d_in[7];
  float* out  = (float*)d_out;
  float* part = (float*)d_ws;

  kv_scatter<<<BATCH, 256, 0, stream>>>(k, v, slot_mapping, k_cache, v_cache);

  // Pick split count that fits the workspace (ws_size is constant -> same
  // grid every call, graph-capture safe).
  int nsplits = 8;
  while (nsplits > 1 &&
         (size_t)BATCH * KVH * nsplits * REC * sizeof(float) > ws_size)
    nsplits >>= 1;

  dim3 grid(nsplits, KVH, BATCH);
  attn_decode<<<grid, 256, 0, stream>>>(q, k_cache, v_cache, block_tables,
                                        context_lens, part, out, nsplits);
  if (nsplits > 1)
    attn_combine<<<dim3(KVH, BATCH), 256, 0, stream>>>(part, out, nsplits);
}

// Round 2
// 505.705 us; speedup vs baseline: 1.0415x; 1.0415x over previous
//
#include <hip/hip_runtime.h>
#include <math.h>

#define BATCH 16
#define NH 32
#define KVH 8
#define NREP 4
#define HD 128
#define BS 16
#define BPS 256
#define MAXSEQ 4096
#define NSPLIT_MAX 32
#define CH 64                 /* tokens per K-tile chunk */
#define KT_STRIDE 33          /* float4 per padded K row (132 floats, uniform bank spread) */
#define ATT_SCALE 0.08838834764831845f
#define REC (NREP * HD + 2 * NREP) /* 520 floats per partial record */

// ---------------------------------------------------------------------------
// Kernel 1: scatter new K/V tokens into the flat-slot view of the caches.
// ---------------------------------------------------------------------------
__global__ __launch_bounds__(256) void kv_scatter(
    const float* __restrict__ k, const float* __restrict__ v,
    const int* __restrict__ slot_mapping,
    float* __restrict__ k_cache, float* __restrict__ v_cache) {
  int b = blockIdx.x;
  int slot = slot_mapping[b];
  size_t base = (size_t)slot * (KVH * HD) + threadIdx.x * 4;
  size_t src = (size_t)b * (KVH * HD) + threadIdx.x * 4;
  *(float4*)(k_cache + base) = *(const float4*)(k + src);
  *(float4*)(v_cache + base) = *(const float4*)(v + src);
}

// ---------------------------------------------------------------------------
// Kernel 2: flash-decode, split-K. grid = (nsplits, KVH, BATCH), 256 threads.
// ---------------------------------------------------------------------------
__global__ __launch_bounds__(256) void attn_decode(
    const float* __restrict__ q,
    const float* __restrict__ k_cache,
    const float* __restrict__ v_cache,
    const int* __restrict__ block_tables,
    const int* __restrict__ context_lens,
    float* __restrict__ part,   // [B][KVH][nsplits][REC]
    float* __restrict__ out,    // used directly when nsplits == 1
    int nsplits) {
  const int split = blockIdx.x;
  const int kvh   = blockIdx.y;
  const int b     = blockIdx.z;
  const int tid   = threadIdx.x;
  const int ctx   = context_lens[b];
  const int span  = MAXSEQ / nsplits;
  const int s_begin = split * span;

  float* rec = part + (((size_t)b * KVH + kvh) * nsplits + split) * REC;

  if (s_begin >= ctx) {
    if (nsplits > 1 && tid < NREP) {
      rec[NREP * HD + tid] = -INFINITY;        // m
      rec[NREP * HD + NREP + tid] = 0.f;       // l
    }
    return;
  }
  const int s_end = min(ctx, s_begin + span);

  __shared__ float4 kt[CH * KT_STRIDE];   // 33792 B K tile (reused as `red` at end)
  __shared__ float4 sq[NREP * 32];        // 2 KB staged Q
  __shared__ float  sc[NREP][CH];         // 1 KB probabilities
  __shared__ int    btab[CH / BS];
  __shared__ float  alpha_sh[NREP], l_sh[NREP];

  const int wave = tid >> 6;
  const int lane = tid & 63;
  const int grp  = tid >> 5;      // 8 PV groups of 32 lanes
  const int gl   = tid & 31;

  if (tid < NREP * 32)
    sq[tid] = *(const float4*)(
        q + ((size_t)b * NH + kvh * NREP + (tid >> 5)) * HD + (tid & 31) * 4);

  float m_w = -INFINITY, l_w = 0.f;   // per-wave (head) softmax state, replicated
  float acc[NREP][4];
#pragma unroll
  for (int h = 0; h < NREP; ++h)
#pragma unroll
    for (int j = 0; j < 4; ++j) acc[h][j] = 0.f;

  const size_t head_off = (size_t)kvh * HD;

  for (int c0 = s_begin; c0 < s_end; c0 += CH) {
    const int n_tok = min(s_end - c0, CH);

    __syncthreads();   // prev chunk's PV reads of sc/btab complete
    if (tid < CH / BS) btab[tid] = block_tables[b * BPS + (c0 >> 4) + tid];
    __syncthreads();

    // ---- Stage K tile: row r covered by 32 lanes x float4 = 512 B contiguous.
    {
      const int c = tid & 31;
      int r = tid >> 5;
#pragma unroll
      for (int i = 0; i < CH / 8; ++i, r += 8) {
        int blk = btab[r >> 4];
        kt[r * KT_STRIDE + c] = *(const float4*)(
            k_cache + ((size_t)blk * BS + (r & 15)) * (KVH * HD) + head_off + c * 4);
      }
    }
    __syncthreads();

    // ---- Scores + online softmax. Zero cross-lane ops in the dot loop.
    {
      const int t = lane;
      const float4* krow = &kt[t * KT_STRIDE];
      const float4* qh = &sq[wave * 32];
      float4 ps = {0.f, 0.f, 0.f, 0.f};
#pragma unroll 8
      for (int c = 0; c < 32; ++c) {
        float4 kk = krow[c];
        float4 qq = qh[c];       // wave-uniform address -> LDS broadcast
        ps.x += kk.x * qq.x;
        ps.y += kk.y * qq.y;
        ps.z += kk.z * qq.z;
        ps.w += kk.w * qq.w;
      }
      const bool valid = t < n_tok;
      float s = (ps.x + ps.y + ps.z + ps.w) * ATT_SCALE;
      float mloc = valid ? s : -INFINITY;
#pragma unroll
      for (int off = 1; off < 64; off <<= 1)
        mloc = fmaxf(mloc, __shfl_xor(mloc, off));
      float m_new = fmaxf(m_w, mloc);
      float e = valid ? __expf(s - m_new) : 0.f;
      float sum = e;
#pragma unroll
      for (int off = 1; off < 64; off <<= 1) sum += __shfl_xor(sum, off);
      float alpha = (m_w == -INFINITY) ? 0.f : __expf(m_w - m_new);
      l_w = l_w * alpha + sum;
      m_w = m_new;
      sc[wave][t] = e;
      if (lane == 0) alpha_sh[wave] = alpha;
    }
    __syncthreads();

    // ---- PV accumulate: group g owns tokens t ≡ g (mod 8).
    {
      float a0 = alpha_sh[0], a1 = alpha_sh[1], a2 = alpha_sh[2], a3 = alpha_sh[3];
#pragma unroll
      for (int j = 0; j < 4; ++j) {
        acc[0][j] *= a0; acc[1][j] *= a1; acc[2][j] *= a2; acc[3][j] *= a3;
      }
      for (int t = grp; t < n_tok; t += 8) {
        int blk = btab[t >> 4];
        const float4 vv = *(const float4*)(
            v_cache + ((size_t)blk * BS + (t & 15)) * (KVH * HD) + head_off + gl * 4);
#pragma unroll
        for (int h = 0; h < NREP; ++h) {
          float pp = sc[h][t];
          acc[h][0] += pp * vv.x;
          acc[h][1] += pp * vv.y;
          acc[h][2] += pp * vv.z;
          acc[h][3] += pp * vv.w;
        }
      }
    }
  }

  // ---- Emit per-head softmax state and cross-group reduction.
  if (lane == 0) {
    l_sh[wave] = l_w;
    if (nsplits > 1) {
      rec[NREP * HD + wave] = m_w;
      rec[NREP * HD + NREP + wave] = l_w;
    }
  }
  float* red = (float*)kt;   // [8 groups][NREP*HD]; aliases kt, barrier-safe
#pragma unroll
  for (int h = 0; h < NREP; ++h)
#pragma unroll
    for (int j = 0; j < 4; ++j)
      red[(grp * NREP + h) * HD + gl * 4 + j] = acc[h][j];
  __syncthreads();

  for (int o = tid; o < NREP * HD; o += 256) {
    float s = 0.f;
#pragma unroll
    for (int g = 0; g < 8; ++g) s += red[(g * NREP) * HD + o];
    int h = o >> 7, d = o & 127;
    if (nsplits == 1) {
      out[((size_t)b * NH + kvh * NREP + h) * HD + d] = s / l_sh[h];
    } else {
      rec[o] = s;
    }
  }
}

// ---------------------------------------------------------------------------
// Kernel 3: merge split partials. grid = (KVH, BATCH), block = 256.
// ---------------------------------------------------------------------------
__global__ __launch_bounds__(256) void attn_combine(
    const float* __restrict__ part, float* __restrict__ out, int nsplits) {
  const int kvh = blockIdx.x;
  const int b   = blockIdx.y;
  const int tid = threadIdx.x;
  const float* base = part + ((size_t)b * KVH + kvh) * nsplits * REC;

  __shared__ float w_sh[NSPLIT_MAX][NREP];
  __shared__ float L_sh[NREP];

  if (tid < NREP) {
    const int h = tid;
    float M = -INFINITY;
    for (int s = 0; s < nsplits; ++s)
      M = fmaxf(M, base[s * REC + NREP * HD + h]);
    float L = 0.f;
    for (int s = 0; s < nsplits; ++s) {
      float m = base[s * REC + NREP * HD + h];
      float l = base[s * REC + NREP * HD + NREP + h];
      float w = (l > 0.f) ? __expf(m - M) : 0.f;
      w_sh[s][h] = w;
      L += l * w;
    }
    L_sh[h] = L;
  }
  __syncthreads();

  for (int o = tid; o < NREP * HD; o += 256) {
    int h = o >> 7, d = o & 127;
    float s = 0.f;
    for (int sp = 0; sp < nsplits; ++sp) {
      float w = w_sh[sp][h];
      if (w > 0.f) s += w * base[sp * REC + o];
    }
    out[((size_t)b * NH + kvh * NREP + h) * HD + d] = s / L_sh[h];
  }
}

// ---------------------------------------------------------------------------
extern "C" void kernel_launch(void* const* d_in, const int* in_sizes, int n_in,
                              void* d_out, int out_size, void* d_ws, size_t ws_size,
                              hipStream_t stream) {
  const float* q = (const float*)d_in[0];
  const float* k = (const float*)d_in[1];
  const float* v = (const float*)d_in[2];
  float* k_cache = (float*)d_in[3];  // mutated; harness restores before each run
  float* v_cache = (float*)d_in[4];
  const int* block_tables = (const int*)d_in[5];
  const int* context_lens = (const int*)d_in[6];
  const int* slot_mapping = (const int*)d_in[7];
  float* out  = (float*)d_out;
  float* part = (float*)d_ws;

  kv_scatter<<<BATCH, 256, 0, stream>>>(k, v, slot_mapping, k_cache, v_cache);

  int nsplits = NSPLIT_MAX;
  while (nsplits > 1 &&
         (size_t)BATCH * KVH * nsplits * REC * sizeof(float) > ws_size)
    nsplits >>= 1;

  dim3 grid(nsplits, KVH, BATCH);
  attn_decode<<<grid, 256, 0, stream>>>(q, k_cache, v_cache, block_tables,
                                        context_lens, part, out, nsplits);
  if (nsplits > 1)
    attn_combine<<<dim3(KVH, BATCH), 256, 0, stream>>>(part, out, nsplits);
}

// Round 3
// 493.107 us; speedup vs baseline: 1.0681x; 1.0255x over previous
//
#include <hip/hip_runtime.h>
#include <math.h>

#define BATCH 16
#define NH 32
#define KVH 8
#define NREP 4
#define HD 128
#define BS 16
#define BPS 256
#define MAXSEQ 4096
#define NSPLITS 32
#define SPAN (MAXSEQ / NSPLITS)   /* 128 tokens per wave */
#define ATT_SCALE 0.08838834764831845f
#define REC (NREP * HD + 2 * NREP) /* 520 floats per partial record (2080 B, 16B-aligned) */

// ---------------------------------------------------------------------------
// 16-lane rotation reduce on the VALU pipe (DPP row_ror) — no LDS ops.
// After 4 steps every lane of the 16-lane row holds the full row sum.
// ---------------------------------------------------------------------------
__device__ __forceinline__ float rowsum16(float x) {
  int t;
  t = __builtin_amdgcn_update_dpp(0, __float_as_int(x), 0x121, 0xf, 0xf, true); // row_ror:1
  x += __int_as_float(t);
  t = __builtin_amdgcn_update_dpp(0, __float_as_int(x), 0x122, 0xf, 0xf, true); // row_ror:2
  x += __int_as_float(t);
  t = __builtin_amdgcn_update_dpp(0, __float_as_int(x), 0x124, 0xf, 0xf, true); // row_ror:4
  x += __int_as_float(t);
  t = __builtin_amdgcn_update_dpp(0, __float_as_int(x), 0x128, 0xf, 0xf, true); // row_ror:8
  x += __int_as_float(t);
  return x;
}

// ---------------------------------------------------------------------------
// Kernel 1: scatter new K/V tokens into the flat-slot view of the caches.
// ---------------------------------------------------------------------------
__global__ __launch_bounds__(256) void kv_scatter(
    const float* __restrict__ k, const float* __restrict__ v,
    const int* __restrict__ slot_mapping,
    float* __restrict__ k_cache, float* __restrict__ v_cache) {
  int b = blockIdx.x;
  int slot = slot_mapping[b];
  size_t base = (size_t)slot * (KVH * HD) + threadIdx.x * 4;
  size_t src = (size_t)b * (KVH * HD) + threadIdx.x * 4;
  *(float4*)(k_cache + base) = *(const float4*)(k + src);
  *(float4*)(v_cache + base) = *(const float4*)(v + src);
}

// ---------------------------------------------------------------------------
// Kernel 2: flash-decode. grid = (NSPLITS/4, KVH, BATCH), 256 threads.
// Wave w of a block owns split blockIdx.x*4+w — waves are FULLY independent:
// no LDS, no barriers. Lane = 16*g + d16: group g owns tokens t≡g (mod 4),
// dim-slice d16 covers dims [d16*8, d16*8+8). Per-group private online
// softmax; groups merged once at the end via 2-step xor shuffles.
// ---------------------------------------------------------------------------
__global__ __launch_bounds__(256, 4) void attn_decode(
    const float* __restrict__ q,
    const float* __restrict__ k_cache,
    const float* __restrict__ v_cache,
    const int* __restrict__ block_tables,
    const int* __restrict__ context_lens,
    float* __restrict__ part) {   // [B][KVH][NSPLITS][REC]
  const int tid  = threadIdx.x;
  const int wave = tid >> 6;
  const int lane = tid & 63;
  const int g    = lane >> 4;
  const int d16  = lane & 15;
  const int kvh  = blockIdx.y;
  const int b    = blockIdx.z;
  const int split = blockIdx.x * 4 + wave;
  const int ctx  = context_lens[b];
  const int s_begin = split * SPAN;

  float* rec = part + (((size_t)b * KVH + kvh) * NSPLITS + split) * REC;

  if (s_begin >= ctx) {
    if (lane < NREP) {
      rec[NREP * HD + lane] = -INFINITY;   // m
      rec[NREP * HD + NREP + lane] = 0.f;  // l
    }
    return;
  }
  const int s_end = min(ctx, s_begin + SPAN);
  const int nb = (s_end - s_begin + BS - 1) >> 4;

  // Q fragments: 4 heads x 8 dims, per lane (32 floats in VGPRs).
  float4 qa[NREP], qb[NREP];
  const float* qp = q + ((size_t)b * NH + kvh * NREP) * HD + d16 * 8;
#pragma unroll
  for (int h = 0; h < NREP; ++h) {
    qa[h] = *(const float4*)(qp + h * HD);
    qb[h] = *(const float4*)(qp + h * HD + 4);
  }

  float m[NREP], l[NREP], acc[NREP][8];
#pragma unroll
  for (int h = 0; h < NREP; ++h) {
    m[h] = -INFINITY;
    l[h] = 0.f;
#pragma unroll
    for (int j = 0; j < 8; ++j) acc[h][j] = 0.f;
  }

  const int* bt = block_tables + b * BPS + (s_begin >> 4);
  const size_t hoff = (size_t)kvh * HD + d16 * 8;

  for (int cb = 0; cb < nb; ++cb) {
    const int blk = bt[cb];
    const size_t pbase = (size_t)blk * BS * (KVH * HD) + hoff;
    const int tbase = s_begin + cb * BS;
#pragma unroll
    for (int i = 0; i < 4; ++i) {
      const int to = i * 4 + g;   // token within the 16-token cache block
      const float* kp = k_cache + pbase + (size_t)to * (KVH * HD);
      const float* vp = v_cache + pbase + (size_t)to * (KVH * HD);
      float4 ka = *(const float4*)kp;
      float4 kb = *(const float4*)(kp + 4);
      float4 va = *(const float4*)vp;
      float4 vb = *(const float4*)(vp + 4);
      const bool valid = (tbase + to) < s_end;
#pragma unroll
      for (int h = 0; h < NREP; ++h) {
        float s = ka.x * qa[h].x + ka.y * qa[h].y + ka.z * qa[h].z + ka.w * qa[h].w
                + kb.x * qb[h].x + kb.y * qb[h].y + kb.z * qb[h].z + kb.w * qb[h].w;
        s = rowsum16(s) * ATT_SCALE;   // all 16 lanes of the group get the sum
        s = valid ? s : -INFINITY;
        if (s > m[h]) {                // group-uniform branch; rare after warmup
          float alpha = __expf(m[h] - s);  // exp(-inf)=0 handles first token
          l[h] *= alpha;
#pragma unroll
          for (int j = 0; j < 8; ++j) acc[h][j] *= alpha;
          m[h] = s;
        }
        float p = valid ? __expf(s - m[h]) : 0.f;
        l[h] += p;
        acc[h][0] += p * va.x; acc[h][1] += p * va.y;
        acc[h][2] += p * va.z; acc[h][3] += p * va.w;
        acc[h][4] += p * vb.x; acc[h][5] += p * vb.y;
        acc[h][6] += p * vb.z; acc[h][7] += p * vb.w;
      }
    }
  }

  // ---- Merge the 4 groups (lanes differing in bits 4-5) and emit partials.
#pragma unroll
  for (int h = 0; h < NREP; ++h) {
    float M = m[h];
    M = fmaxf(M, __shfl_xor(M, 16));
    M = fmaxf(M, __shfl_xor(M, 32));
    float w = (m[h] == -INFINITY) ? 0.f : __expf(m[h] - M);
    float lw = l[h] * w;
    lw += __shfl_xor(lw, 16);
    lw += __shfl_xor(lw, 32);
#pragma unroll
    for (int j = 0; j < 8; ++j) {
      float a = acc[h][j] * w;
      a += __shfl_xor(a, 16);
      a += __shfl_xor(a, 32);
      acc[h][j] = a;
    }
    if (lane == 0) {
      rec[NREP * HD + h] = M;          // finite: wave has >=1 valid token
      rec[NREP * HD + NREP + h] = lw;
    }
    if (g == 0) {                      // 16 lanes cover this head's 128 dims
      float* rp = rec + h * HD + d16 * 8;
      *(float4*)rp = make_float4(acc[h][0], acc[h][1], acc[h][2], acc[h][3]);
      *(float4*)(rp + 4) = make_float4(acc[h][4], acc[h][5], acc[h][6], acc[h][7]);
    }
  }
}

// ---------------------------------------------------------------------------
// Kernel 3: merge split partials. grid = (KVH, BATCH), block = 256.
// ---------------------------------------------------------------------------
__global__ __launch_bounds__(256) void attn_combine(
    const float* __restrict__ part, float* __restrict__ out) {
  const int kvh = blockIdx.x;
  const int b   = blockIdx.y;
  const int tid = threadIdx.x;
  const float* base = part + ((size_t)b * KVH + kvh) * NSPLITS * REC;

  __shared__ float w_sh[NSPLITS][NREP];
  __shared__ float L_sh[NREP];

  if (tid < NREP) {
    const int h = tid;
    float M = -INFINITY;
    for (int s = 0; s < NSPLITS; ++s)
      M = fmaxf(M, base[s * REC + NREP * HD + h]);
    float L = 0.f;
    for (int s = 0; s < NSPLITS; ++s) {
      float m = base[s * REC + NREP * HD + h];
      float l = base[s * REC + NREP * HD + NREP + h];
      float w = (l > 0.f) ? __expf(m - M) : 0.f;
      w_sh[s][h] = w;
      L += l * w;
    }
    L_sh[h] = L;
  }
  __syncthreads();

  for (int o = tid; o < NREP * HD; o += 256) {
    int h = o >> 7, d = o & 127;
    float s = 0.f;
    for (int sp = 0; sp < NSPLITS; ++sp) {
      float w = w_sh[sp][h];
      if (w > 0.f) s += w * base[sp * REC + o];
    }
    out[((size_t)b * NH + kvh * NREP + h) * HD + d] = s / L_sh[h];
  }
}

// ---------------------------------------------------------------------------
extern "C" void kernel_launch(void* const* d_in, const int* in_sizes, int n_in,
                              void* d_out, int out_size, void* d_ws, size_t ws_size,
                              hipStream_t stream) {
  const float* q = (const float*)d_in[0];
  const float* k = (const float*)d_in[1];
  const float* v = (const float*)d_in[2];
  float* k_cache = (float*)d_in[3];  // mutated; harness restores before each run
  float* v_cache = (float*)d_in[4];
  const int* block_tables = (const int*)d_in[5];
  const int* context_lens = (const int*)d_in[6];
  const int* slot_mapping = (const int*)d_in[7];
  float* out  = (float*)d_out;
  float* part = (float*)d_ws;   // needs 16*8*32*520*4 = 8.5 MB

  kv_scatter<<<BATCH, 256, 0, stream>>>(k, v, slot_mapping, k_cache, v_cache);

  dim3 grid(NSPLITS / 4, KVH, BATCH);
  attn_decode<<<grid, 256, 0, stream>>>(q, k_cache, v_cache, block_tables,
                                        context_lens, part);
  attn_combine<<<dim3(KVH, BATCH), 256, 0, stream>>>(part, out);
}